// Round 3
// baseline (140.523 us; speedup 1.0000x reference)
//
#include <hip/hip_runtime.h>
#include <hip/hip_bf16.h>
#include <math.h>

// Problem constants (B=512, D=768, H=256)
#define B 512
#define D 768
#define H 256
#define NN 128          // n = B/4
#define MM 256          // m = B/2
#define P_PAIRS 57280   // sum_{i=0}^{127} (511 - i)

typedef __attribute__((ext_vector_type(8))) __bf16 bf16x8;
typedef __attribute__((ext_vector_type(4))) __bf16 bf16x4;
typedef __attribute__((ext_vector_type(4))) float f32x4;

// MFMA 16x16x32 bf16 layouts (verified):
//   A[m = lane&15][k = (lane>>4)*8 + j]  (8 bf16/lane, contiguous k)
//   B[k][n] loaded from row-major [n][k] with the same per-lane pattern
//   C/D: col = lane&15, row = (lane>>4)*4 + reg

// ---------------- K1: normalize z -> bf16, W1/W2 -> bf16, zero stats ----------------
// W1b[n][k] (n in [0,512)) = W1[n&255][(n>>8)*768 + k]  (stacked U|V weight rows)
__global__ __launch_bounds__(256) void k_prep(const float* __restrict__ emb,
                                              const float* __restrict__ W1,
                                              const float* __restrict__ W2,
                                              __bf16* __restrict__ zbf,
                                              __bf16* __restrict__ W1b,
                                              __bf16* __restrict__ W2b,
                                              float* __restrict__ stats) {
    int bx = blockIdx.x;
    int t = threadIdx.x;
    if (bx < B) {
        // normalize row bx
        float4 v4 = make_float4(0.f, 0.f, 0.f, 0.f);
        float ss = 0.f;
        if (t < D / 4) {
            v4 = *(const float4*)(emb + bx * D + 4 * t);
            ss = v4.x * v4.x + v4.y * v4.y + v4.z * v4.z + v4.w * v4.w;
        }
        __shared__ float red[256];
        red[t] = ss;
        __syncthreads();
        for (int s = 128; s > 0; s >>= 1) {
            if (t < s) red[t] += red[t + s];
            __syncthreads();
        }
        float inv = 1.0f / fmaxf(sqrtf(red[0]), 1e-12f);
        if (t < D / 4) {
            bf16x4 o;
            o[0] = (__bf16)(v4.x * inv); o[1] = (__bf16)(v4.y * inv);
            o[2] = (__bf16)(v4.z * inv); o[3] = (__bf16)(v4.w * inv);
            *(bf16x4*)(zbf + bx * D + 4 * t) = o;
        }
    } else if (bx < B + 64) {
        // W2 convert: 64 blocks x 256 thr x 4 el
        int e4 = (bx - B) * 256 + t;     // 0..16383
        float4 w = *(const float4*)(W2 + 4 * e4);
        bf16x4 o;
        o[0] = (__bf16)w.x; o[1] = (__bf16)w.y; o[2] = (__bf16)w.z; o[3] = (__bf16)w.w;
        *(bf16x4*)(W2b + 4 * e4) = o;
    } else if (bx < B + 64 + 2 * H) {
        // W1 convert+restack: one block per output row n in [0,512)
        int n = bx - B - 64;
        if (t < D / 4) {
            float4 w = *(const float4*)(W1 + (n & 255) * (2 * D) + (n >> 8) * D + 4 * t);
            bf16x4 o;
            o[0] = (__bf16)w.x; o[1] = (__bf16)w.y; o[2] = (__bf16)w.z; o[3] = (__bf16)w.w;
            *(bf16x4*)(W1b + n * D + 4 * t) = o;
        }
    } else {
        // zero expsum[128], slog[128], bce, counter
        stats[t] = 0.f;
        if (t == 0) { stats[256] = 0.f; ((int*)stats)[257] = 0; }
    }
}

// ---------------- K2: fused similarity stats + U'/V GEMMs ----------------
// blocks [0,32):  sim — m-tile 16 (rows<128), per-wave n-tile 64
// blocks [32,160): uv — m-tile 32 (2 waves x 16 rows), n-tile 64, B = W1b (bf16)
__global__ __launch_bounds__(128) void k_sim_uv(const __bf16* __restrict__ zbf,
                                                const __bf16* __restrict__ W1b,
                                                const float* __restrict__ b1,
                                                __bf16* __restrict__ Up,
                                                __bf16* __restrict__ Vv,
                                                float* __restrict__ expsum,
                                                float* __restrict__ slog) {
    int bx = blockIdx.x;
    int w = threadIdx.x >> 6;
    int lane = threadIdx.x & 63;
    int r = lane & 15, q = lane >> 4;

    if (bx < 32) {
        // ---- similarity stats ----
        int m0 = (bx >> 2) * 16;
        int n0 = (bx & 3) * 128 + w * 64;
        f32x4 acc[4] = {};
        const __bf16* Ab = zbf + (m0 + r) * D + 8 * q;
        for (int s = 0; s < D / 32; s++) {
            bf16x8 a = *(const bf16x8*)(Ab + 32 * s);
            #pragma unroll
            for (int nt = 0; nt < 4; nt++) {
                bf16x8 b = *(const bf16x8*)(zbf + (n0 + 16 * nt + r) * D + 8 * q + 32 * s);
                acc[nt] = __builtin_amdgcn_mfma_f32_16x16x32_bf16(a, b, acc[nt], 0, 0, 0);
            }
        }
        #pragma unroll
        for (int rr = 0; rr < 4; rr++) {
            int irow = m0 + q * 4 + rr;
            float es = 0.f, sl = 0.f;
            #pragma unroll
            for (int nt = 0; nt < 4; nt++) {
                int kcol = n0 + nt * 16 + r;
                float C = acc[nt][rr];
                if (kcol != irow) es += expf(2.f * C);
                if (kcol > irow && kcol < NN) sl += 2.f * C;
            }
            #pragma unroll
            for (int m = 1; m <= 8; m <<= 1) {
                es += __shfl_xor(es, m);
                sl += __shfl_xor(sl, m);
            }
            if (r == 0) {
                atomicAdd(&expsum[irow], es);
                atomicAdd(&slog[irow], sl);
            }
        }
    } else {
        // ---- U' = z@W1a^T + b1 ; V = z@W1b^T  (outputs bf16) ----
        int bxu = bx - 32;
        int m0 = (bxu >> 3) * 32 + 16 * w;
        int n0 = (bxu & 7) * 64;
        f32x4 acc[4] = {};
        const __bf16* Ab = zbf + (m0 + r) * D + 8 * q;
        for (int s = 0; s < D / 32; s++) {
            bf16x8 a = *(const bf16x8*)(Ab + 32 * s);
            #pragma unroll
            for (int nt = 0; nt < 4; nt++) {
                bf16x8 b = *(const bf16x8*)(W1b + (n0 + 16 * nt + r) * D + 8 * q + 32 * s);
                acc[nt] = __builtin_amdgcn_mfma_f32_16x16x32_bf16(a, b, acc[nt], 0, 0, 0);
            }
        }
        #pragma unroll
        for (int nt = 0; nt < 4; nt++) {
            int n = n0 + 16 * nt + r;
            float bias = (n < H) ? b1[n] : 0.f;
            #pragma unroll
            for (int rr = 0; rr < 4; rr++) {
                int m = m0 + 4 * q + rr;
                float C = acc[nt][rr] + bias;
                if (n < H) Up[m * H + n] = (__bf16)C;
                else       Vv[m * H + (n - H)] = (__bf16)C;
            }
        }
    }
}

// ---------------- K3: pair MLP, register-resident W2, 4 i's per block ----------------
// grid (8 j-tiles of 64, 32 i-quads), 256 threads (4 waves, wave w -> cols 64w..64w+63)
__global__ __launch_bounds__(256, 2) void k_pairs(const __bf16* __restrict__ Up,
                                                  const __bf16* __restrict__ Vv,
                                                  const __bf16* __restrict__ W2b,
                                                  const float* __restrict__ b2,
                                                  const float* __restrict__ W3,
                                                  const float* __restrict__ b3,
                                                  float* __restrict__ expsum,
                                                  float* __restrict__ slog,
                                                  float* __restrict__ bce,
                                                  int* __restrict__ counter,
                                                  float* __restrict__ out) {
    __shared__ __bf16 h1[64][264];       // 33.8 KB, stride 528B (2-way banks: free)
    __shared__ float redbuf[4][64];
    __shared__ float red[128];
    __shared__ int islast;

    int tid = threadIdx.x;
    int w = tid >> 6, lane = tid & 63;
    int r = lane & 15, q = lane >> 4;
    int j0 = blockIdx.x * 64;
    int ig = blockIdx.y;
    bool active = (j0 + 63 > 4 * ig);    // any j > smallest i in quad

    float lsum = 0.f;
    if (active) {
        // W2 slice for this wave: 64 cols x 256 k, resident in 128 VGPRs
        bf16x8 Bf[4][8];
        float b2v[4], w3v[4];
        #pragma unroll
        for (int nt = 0; nt < 4; nt++) {
            int n = 64 * w + 16 * nt + r;
            #pragma unroll
            for (int s = 0; s < 8; s++)
                Bf[nt][s] = *(const bf16x8*)(W2b + n * H + 32 * s + 8 * q);
            b2v[nt] = b2[n];
            w3v[nt] = W3[n];
        }
        float b3v = b3[0];

        int srow = tid & 63;             // staging: row j0+srow
        int scol0 = (tid >> 6) * 64;     // 64 cols per thread

        #pragma unroll 1
        for (int ii = 0; ii < 4; ii++) {
            int i = ig * 4 + ii;
            // ---- stage h1 = relu(U'[i] + V[j]) (bf16) ----
            #pragma unroll
            for (int c8 = 0; c8 < 8; c8++) {
                int col = scol0 + 8 * c8;
                bf16x8 vv8 = *(const bf16x8*)(Vv + (j0 + srow) * H + col);
                bf16x8 uu8 = *(const bf16x8*)(Up + i * H + col);
                bf16x8 hv;
                #pragma unroll
                for (int e = 0; e < 8; e++)
                    hv[e] = (__bf16)fmaxf((float)uu8[e] + (float)vv8[e], 0.f);
                *(bf16x8*)&h1[srow][col] = hv;
            }
            __syncthreads();

            // ---- MFMA: C = h1 @ W2^T (64x64 per wave) ----
            f32x4 acc[4][4] = {};        // [mt][nt]
            #pragma unroll
            for (int s = 0; s < 8; s++) {
                bf16x8 a[4];
                #pragma unroll
                for (int mt = 0; mt < 4; mt++)
                    a[mt] = *(const bf16x8*)&h1[16 * mt + r][32 * s + 8 * q];
                #pragma unroll
                for (int mt = 0; mt < 4; mt++)
                    #pragma unroll
                    for (int nt = 0; nt < 4; nt++)
                        acc[mt][nt] = __builtin_amdgcn_mfma_f32_16x16x32_bf16(a[mt], Bf[nt][s], acc[mt][nt], 0, 0, 0);
            }

            // ---- epilogue: relu(+b2), dot W3, reduce ----
            float part[4][4];            // [mt][rr]
            #pragma unroll
            for (int mt = 0; mt < 4; mt++)
                #pragma unroll
                for (int rr = 0; rr < 4; rr++) part[mt][rr] = 0.f;
            #pragma unroll
            for (int nt = 0; nt < 4; nt++)
                #pragma unroll
                for (int mt = 0; mt < 4; mt++)
                    #pragma unroll
                    for (int rr = 0; rr < 4; rr++) {
                        float h2 = fmaxf(acc[mt][nt][rr] + b2v[nt], 0.f);
                        part[mt][rr] += h2 * w3v[nt];
                    }
            #pragma unroll
            for (int mt = 0; mt < 4; mt++)
                #pragma unroll
                for (int rr = 0; rr < 4; rr++) {
                    float v = part[mt][rr];
                    #pragma unroll
                    for (int m = 1; m <= 8; m <<= 1) v += __shfl_xor(v, m);
                    if (r == 0) redbuf[w][16 * mt + 4 * q + rr] = v;
                }
            __syncthreads();

            if (tid < 64) {
                int j = j0 + tid;
                if (j > i) {
                    float logit = redbuf[0][tid] + redbuf[1][tid] +
                                  redbuf[2][tid] + redbuf[3][tid] + b3v;
                    float label = (j < MM) ? 1.f : 0.f;
                    lsum += fmaxf(logit, 0.f) - logit * label +
                            log1pf(expf(-fabsf(logit)));
                }
            }
            __syncthreads();             // h1/redbuf reuse hazard
        }

        if (tid < 64) {
            #pragma unroll
            for (int off = 32; off > 0; off >>= 1) lsum += __shfl_down(lsum, off);
            if (tid == 0) atomicAdd(bce, lsum);
        }
    }

    // ---- last-block final combine ----
    __threadfence();
    if (tid == 0) {
        int old = atomicAdd(counter, 1);
        islast = (old == 8 * 32 - 1);
    }
    __syncthreads();
    if (islast) {
        if (tid < 128)
            red[tid] = (float)(NN - 1 - tid) * logf(expsum[tid]) - slog[tid];
        __syncthreads();
        for (int s = 64; s > 0; s >>= 1) {
            if (tid < s && tid + s < 128) red[tid] += red[tid + s];
            __syncthreads();
        }
        if (tid == 0) {
            float closs = (-2.0f * (float)(NN - 1) / (float)NN) * red[0];
            float bv = atomicAdd(bce, 0.f);   // device-scope atomic read
            out[0] = closs + bv / (float)P_PAIRS;
        }
    }
}

extern "C" void kernel_launch(void* const* d_in, const int* in_sizes, int n_in,
                              void* d_out, int out_size, void* d_ws, size_t ws_size,
                              hipStream_t stream) {
    const float* emb = (const float*)d_in[0];
    const float* W1  = (const float*)d_in[1];
    const float* b1  = (const float*)d_in[2];
    const float* W2  = (const float*)d_in[3];
    const float* b2  = (const float*)d_in[4];
    const float* W3  = (const float*)d_in[5];
    const float* b3  = (const float*)d_in[6];
    float* out = (float*)d_out;

    // Workspace layout
    float* ws = (float*)d_ws;
    float* stats  = ws;                          // expsum[128] | slog[128] | bce | counter
    float* expsum = ws;
    float* slog   = ws + 128;
    float* bce    = ws + 256;
    int*   counter= (int*)(ws + 257);
    __bf16* zbf = (__bf16*)(ws + 512);           // 512*768
    __bf16* W1b = zbf + B * D;                   // 512*768
    __bf16* W2b = W1b + 2 * H * D;               // 256*256
    __bf16* Up  = W2b + H * H;                   // 512*256
    __bf16* Vv  = Up + B * H;                    // 512*256

    k_prep<<<B + 64 + 2 * H + 1, 256, 0, stream>>>(emb, W1, W2, zbf, W1b, W2b, stats);
    k_sim_uv<<<160, 128, 0, stream>>>(zbf, W1b, b1, Up, Vv, expsum, slog);
    k_pairs<<<dim3(8, 32), 256, 0, stream>>>(Up, Vv, W2b, b2, W3, b3,
                                             expsum, slog, bce, counter, out);
}